// Round 17
// baseline (448.242 us; speedup 1.0000x reference)
//
#include <hip/hip_runtime.h>
#include <hip/hip_bf16.h>

#define NTOK   4096
#define DMODEL 1024
#define DFF    4096
#define NEXP   8
#define TOPK   2
#define NSLOT   (NTOK*TOPK)            // 8192
#define MAXSLOT (NSLOT + NEXP*256)     // 10240 (256-aligned packing)
#define NT2     40                     // max 256-row tiles = 8 XCDs * 5
#define NT1     72                     // max 128-row tiles = 8 XCDs * 9
#define NWTILE  8192                   // 64x64 tiles per weight tensor

typedef __attribute__((ext_vector_type(8))) short bf16x8;
typedef __attribute__((ext_vector_type(8))) unsigned short u16x8;
typedef __attribute__((ext_vector_type(4))) float f32x4;

__device__ __forceinline__ unsigned short f2bf(float f){
    union { float f; unsigned int u; } v; v.f = f;
    unsigned int r = (v.u + 0x7fffu + ((v.u >> 16) & 1u)) >> 16;
    return (unsigned short)r;
}

__device__ __forceinline__ void gload16(const unsigned short* g, unsigned short* l){
    __builtin_amdgcn_global_load_lds(
        (const __attribute__((address_space(1))) void*)g,
        (__attribute__((address_space(3))) void*)l,
        16, 0, 0);
}

#define WAITLGKM() asm volatile("s_waitcnt lgkmcnt(0)" ::: "memory")
#define WAITVM4()  asm volatile("s_waitcnt vmcnt(4)" ::: "memory")
#define WAITVM0()  asm volatile("s_waitcnt vmcnt(0)" ::: "memory")
#define SCHEDPIN() __builtin_amdgcn_sched_barrier(0)
#define MFMA16(a,b,c) __builtin_amdgcn_mfma_f32_16x16x32_bf16(a,b,c,0,0,0)

// proven 3-bit XOR involution read (rows stride 64 shorts = 128 B):
// phys 16B-chunk = logical ^ (r&7)  -> 16-lane read phase = 8 slots x 2 lanes (free)
__device__ __forceinline__ bf16x8 ldswz(const unsigned short* lds, int base, int r, int kcol){
    return *(const bf16x8*)&lds[base + r*64 + (kcol ^ ((r & 7) << 3))];
}

// ---- 64x64 fp32-LDS transpose-convert tile (256-thread) ----
__device__ __forceinline__ void transpose_tile64(const float* __restrict__ src,
                                                 unsigned short* __restrict__ dst,
                                                 int R, int C, int r0, int c0,
                                                 float (*tile)[65])
{
    int t = threadIdx.x;
    int tr  = t >> 4;          // 0..15
    int tc4 = (t & 15) * 4;    // 0..60
    #pragma unroll
    for(int i=0;i<4;i++){
        float4 v = *(const float4*)&src[(size_t)(r0 + tr + i*16)*C + c0 + tc4];
        tile[tc4+0][tr + i*16] = v.x;
        tile[tc4+1][tr + i*16] = v.y;
        tile[tc4+2][tr + i*16] = v.z;
        tile[tc4+3][tr + i*16] = v.w;
    }
    __syncthreads();
    int cr = t >> 3;           // 0..31
    int rb = (t & 7) * 8;      // 0..56
    #pragma unroll
    for(int i=0;i<2;i++){
        int c = cr + i*32;
        u16x8 o;
        #pragma unroll
        for(int q=0;q<8;q++) o[q] = f2bf(tile[c][rb + q]);
        *(u16x8*)&dst[(size_t)(c0 + c)*R + r0 + rb] = o;
    }
    __syncthreads();
}

// ---------------- fused: gating (+x convert + out zero) ∥ W1 transpose-convert ----------------
__global__ __launch_bounds__(256) void k_gate_w1t(const float* __restrict__ x,
                                                  const float* __restrict__ Wg,
                                                  const float* __restrict__ bg,
                                                  const float* __restrict__ W1,
                                                  unsigned short* __restrict__ Xb,
                                                  unsigned short* __restrict__ W1t,
                                                  float* __restrict__ out,
                                                  int* __restrict__ token_e,
                                                  float* __restrict__ token_w,
                                                  int* __restrict__ cnt)
{
    __shared__ float tile[64][65];
    int bx = blockIdx.x;
    if(bx % 3 != 0){
        int w = bx - bx/3 - 1;                 // 0..2047
        for(int t2 = w; t2 < NWTILE; t2 += 2048){
            int z  = t2 >> 10;
            int rem = t2 & 1023;
            int rt = rem >> 6;                 // 0..15
            int ct = rem & 63;                 // 0..63
            transpose_tile64(W1 + (size_t)z*DMODEL*DFF, W1t + (size_t)z*DMODEL*DFF,
                             DMODEL, DFF, rt*64, ct*64, tile);
        }
        return;
    }
    int b = bx / 3;
    int tid = threadIdx.x;
    const float4* xs = (const float4*)x + (size_t)b * 1024;
    ushort4* xd = (ushort4*)Xb + (size_t)b * 1024;
    float4* oz = (float4*)out + (size_t)b * 1024;
    float4 z4 = {0.f,0.f,0.f,0.f};
    #pragma unroll
    for(int rep=0;rep<4;rep++){
        float4 v = xs[rep*256 + tid];
        ushort4 o; o.x=f2bf(v.x); o.y=f2bf(v.y); o.z=f2bf(v.z); o.w=f2bf(v.w);
        xd[rep*256 + tid] = o;
        oz[rep*256 + tid] = z4;
    }

    int wid = tid >> 6, lane = tid & 63;
    int t = b * 4 + wid;
    const float* xr = x + (size_t)t * DMODEL;
    float pe[NEXP];
    #pragma unroll
    for(int e=0;e<NEXP;e++) pe[e] = 0.f;
    for(int i=0;i<DMODEL/64;i++){
        int d = i*64 + lane;
        float xv = xr[d];
        const float* wr = Wg + (size_t)d * NEXP;
        #pragma unroll
        for(int e=0;e<NEXP;e++) pe[e] += xv * wr[e];
    }
    #pragma unroll
    for(int off=32; off>0; off>>=1){
        #pragma unroll
        for(int e=0;e<NEXP;e++) pe[e] += __shfl_xor(pe[e], off);
    }
    if(lane == 0){
        float lg[NEXP], mx = -1e30f;
        #pragma unroll
        for(int e=0;e<NEXP;e++){ lg[e] = pe[e] + bg[e]; mx = fmaxf(mx, lg[e]); }
        float pr[NEXP];
        #pragma unroll
        for(int e=0;e<NEXP;e++) pr[e] = expf(lg[e] - mx);
        int e0 = 0; float p0 = pr[0];
        #pragma unroll
        for(int e=1;e<NEXP;e++) if(pr[e] > p0){ p0 = pr[e]; e0 = e; }
        int e1 = -1; float p1 = -1.f;
        #pragma unroll
        for(int e=0;e<NEXP;e++) if(e != e0 && pr[e] > p1){ p1 = pr[e]; e1 = e; }
        float dn = p0 + p1;
        token_e[2*t]   = e0; token_w[2*t]   = p0/dn;
        token_e[2*t+1] = e1; token_w[2*t+1] = p1/dn;
        atomicAdd(&cnt[e0], 1); atomicAdd(&cnt[e1], 1);
    }
}

// ---------------- prefix: both tile tables (256 & 128) + cursors + pad prefill ----------------
__global__ __launch_bounds__(256) void k_prefix(const int* __restrict__ cnt,
                                                int* __restrict__ t2e, int* __restrict__ t2r,
                                                int* __restrict__ t2v,
                                                int* __restrict__ t1e, int* __restrict__ t1r,
                                                int* __restrict__ t1v,
                                                int* __restrict__ cursor,
                                                int* __restrict__ slot_token)
{
    int tid = threadIdx.x;
    if(tid == 0){
        int off = 0, n2 = 0, n1 = 0;
        for(int e=0;e<NEXP;e++){
            cursor[e] = off;
            int c = cnt[e];
            for(int r=0;r<c;r+=256){
                t2e[n2] = e; t2r[n2] = off + r;
                t2v[n2] = (c - r < 256) ? (c - r) : 256; n2++;
            }
            for(int r=0;r<c;r+=128){
                t1e[n1] = e; t1r[n1] = off + r;
                t1v[n1] = (c - r < 128) ? (c - r) : 128; n1++;
            }
            off += ((c + 255)/256)*256;
        }
        for(int i=n2;i<NT2;i++){ t2e[i]=0; t2r[i]=0; t2v[i]=0; }
        for(int i=n1;i<NT1;i++){ t1e[i]=0; t1r[i]=0; t1v[i]=0; }
    }
    for(int s=tid; s<MAXSLOT; s+=256) slot_token[s] = 0;
}

// ---------------- scatter: 32 blocks, global cursor atomics ----------------
__global__ __launch_bounds__(256) void k_scatter(const int* __restrict__ token_e,
                                                 const float* __restrict__ token_w,
                                                 int* __restrict__ cursor,
                                                 int* __restrict__ slot_token,
                                                 float* __restrict__ slot_w)
{
    int i = blockIdx.x*256 + threadIdx.x;
    int e = token_e[i];
    int s = atomicAdd(&cursor[e], 1);
    slot_token[s] = i >> 1;
    slot_w[s] = token_w[i];
}

// ---------------- GEMM1: 256x256 8-wave, 4-phase/K-tile fine-interleaved counted-vmcnt ----------------
// R3's verified-correct schedule + CORRECT 3-bit swizzle (the untested combination).
// y<4: W2-transpose rider (256 streams x exactly 32 tiles, divergence-free).
__global__ __launch_bounds__(512, 1) void k_gemm1(const unsigned short* __restrict__ A,
                                                  const unsigned short* __restrict__ Bw,
                                                  const float* __restrict__ bias,
                                                  const int* __restrict__ t2e,
                                                  const int* __restrict__ t2r,
                                                  const int* __restrict__ t2v,
                                                  const int* __restrict__ slot_token,
                                                  unsigned short* __restrict__ OutH,
                                                  const float* __restrict__ W2,
                                                  unsigned short* __restrict__ W2t)
{
    __shared__ unsigned short lds[65536];   // 128 KB: [buf:2][A|B][256][64] bf16

    int t = threadIdx.x;
    int y = blockIdx.y;
    if(y < 4){                              // -------- W2 transpose rider --------
        if(blockIdx.x >= 32) return;
        int half = t >> 8, tl = t & 255;
        float* fl = (float*)lds;
        float (*tile)[65] = (float(*)[65])(fl + half*64*65);
        int stream = (blockIdx.x*4 + y)*2 + half;      // 0..255
        int tr = tl >> 4, tc4 = (tl & 15)*4;
        int cr = tl >> 3, rb = (tl & 7)*8;
        for(int j=0;j<32;j++){
            int t2 = stream + j*256;                   // 8192/256 = 32 exact
            int z = t2 >> 10, rem = t2 & 1023;
            const float* src = W2 + (size_t)z*DFF*DMODEL;
            unsigned short* dst = W2t + (size_t)z*DFF*DMODEL;
            int r0 = (rem >> 4)*64, c0 = (rem & 15)*64;
            #pragma unroll
            for(int i=0;i<4;i++){
                float4 v = *(const float4*)&src[(size_t)(r0 + tr + i*16)*DMODEL + c0 + tc4];
                tile[tc4+0][tr+i*16]=v.x; tile[tc4+1][tr+i*16]=v.y;
                tile[tc4+2][tr+i*16]=v.z; tile[tc4+3][tr+i*16]=v.w;
            }
            __syncthreads();
            #pragma unroll
            for(int i=0;i<2;i++){
                int c = cr + i*32;
                u16x8 o;
                #pragma unroll
                for(int q=0;q<8;q++) o[q] = f2bf(tile[c][rb+q]);
                *(u16x8*)&dst[(size_t)(c0 + c)*DFF + r0 + rb] = o;
            }
            __syncthreads();
        }
        return;
    }

    int xb = blockIdx.x;
    int tid = (xb & 7) * 5 + (xb >> 3);     // XCD-chunked bijective swizzle (40 = 8*5)
    int valid = t2v[tid];
    if(valid == 0) return;
    int e = t2e[tid], row0 = t2r[tid];
    int n0 = (y - 4) * 256;
    const int K = DMODEL, N = DFF;
    const unsigned short* Be = Bw + (size_t)e * N * K;

    int lane = t & 63, wid = t >> 6;
    int wm = wid >> 2, wn = wid & 3;
    int rl = lane & 15, g = lane >> 4;

    // staging: (half h, round l): row r = h*128 + l*64 + (t>>3), phys chunk t&7;
    // source chunk = (t&7) ^ (r&7) = (t&7) ^ ((t>>3)&7)  [r&7 indep of h,l]
    int r8  = t >> 3;
    int ccs = (t & 7) ^ (r8 & 7);
    const unsigned short* asrc[2][2];
    const unsigned short* bsrc[2][2];
    #pragma unroll
    for(int h=0;h<2;h++){
        #pragma unroll
        for(int l=0;l<2;l++){
            int r = h*128 + l*64 + r8;
            size_t ar = (size_t)slot_token[row0 + r] * (size_t)K;
            asrc[h][l] = A  + ar + ccs*8;
            bsrc[h][l] = Be + (size_t)(n0 + r)*K + ccs*8;
        }
    }
    int ldst = t * 8;

#define SA1(kt,h,l) gload16(asrc[h][l] + (kt)*64, &lds[(((kt)&1)<<15) + ((h)<<13) + ((l)<<12) + ldst])
#define SB1(kt,h,l) gload16(bsrc[h][l] + (kt)*64, &lds[(((kt)&1)<<15) + 16384 + ((h)<<13) + ((l)<<12) + ldst])

    // prologue: T0 fully, T1 B-halves (12 loads)
    SA1(0,0,0); SA1(0,0,1); SA1(0,1,0); SA1(0,1,1);
    SB1(0,0,0); SB1(0,0,1); SB1(0,1,0); SB1(0,1,1);
    SB1(1,0,0); SB1(1,0,1); SB1(1,1,0); SB1(1,1,1);

    f32x4 acc[8][4];
    #pragma unroll
    for(int i=0;i<8;i++)
        #pragma unroll
        for(int j=0;j<4;j++) acc[i][j] = (f32x4){0.f,0.f,0.f,0.f};

    WAITVM4();                          // T0 landed (T1's 4 B-loads may fly)
    __builtin_amdgcn_s_barrier();

    const int NK = K >> 6;              // 16
    bf16x8 af[4][2], bfv[4][2];

    for(int k=0;k<NK;k++){
        int bufo = (k & 1) << 15;
        bool stA = (k+1 < NK);          // T(k+1) A -> other buf (its A-reads ended last iter)
        bool stB = (k+2 < NK);          // T(k+2) B -> this buf (B-reads end at P2 barrier)

        // ---- P1: read A(mh0) + B(n0,n1); stage A(k+1)h0; MFMA (mh0, nh0)
        #pragma unroll
        for(int m=0;m<4;m++){
            af[m][0] = ldswz(lds, bufo, wm*128 + m*16 + rl, g*8);
            af[m][1] = ldswz(lds, bufo, wm*128 + m*16 + rl, 32 + g*8);
        }
        #pragma unroll
        for(int n=0;n<2;n++){
            bfv[n][0] = ldswz(lds, bufo + 16384, wn*64 + n*16 + rl, g*8);
            bfv[n][1] = ldswz(lds, bufo + 16384, wn*64 + n*16 + rl, 32 + g*8);
        }
        if(stA){ SA1(k+1,0,0); SA1(k+1,0,1); }
        __builtin_amdgcn_s_barrier();
        WAITLGKM();
        SCHEDPIN();
        __builtin_amdgcn_s_setprio(1);
        #pragma unroll
        for(int m=0;m<4;m++)
            #pragma unroll
            for(int n=0;n<2;n++){
                acc[m][n] = MFMA16(af[m][0], bfv[n][0], acc[m][n]);
                acc[m][n] = MFMA16(af[m][1], bfv[n][1], acc[m][n]);
            }
        __builtin_amdgcn_s_setprio(0);
        __builtin_amdgcn_s_barrier();

        // ---- P2: read B(n2,n3); stage A(k+1)h1; MFMA (mh0, nh1)
        #pragma unroll
        for(int n=2;n<4;n++){
            bfv[n][0] = ldswz(lds, bufo + 16384, wn*64 + n*16 + rl, g*8);
            bfv[n][1] = ldswz(lds, bufo + 16384, wn*64 + n*16 + rl, 32 + g*8);
        }
        if(stA){ SA1(k+1,1,0); SA1(k+1,1,1); }
        __builtin_amdgcn_s_barrier();
        WAITLGKM();
        SCHEDPIN();
        __builtin_amdgcn_s_setprio(1);
        #pragma unroll
        for(int m=0;m<4;m++)
            #pragma unroll
            for(int n=2;n<4;n++){
                acc[m][n] = MFMA16(af[m][0], bfv[n][0], acc[m][n]);
                acc[m][n] = MFMA16(af[m][1], bfv[n][1], acc[m][n]);
            }
        __builtin_amdgcn_s_setprio(0);
        __builtin_amdgcn_s_barrier();

        // ---- P3: read A(mh1); stage B(k+2)h0; MFMA (mh1, nh0)
        #pragma unroll
        for(int m=0;m<4;m++){
            af[m][0] = ldswz(lds, bufo, wm*128 + 64 + m*16 + rl, g*8);
            af[m][1] = ldswz(lds, bufo, wm*128 + 64 + m*16 + rl, 32 + g*8);
        }
        if(stB){ SB1(k+2,0,0); SB1(k+2,0,1); }
        __builtin_amdgcn_s_barrier();
        WAITLGKM();
        SCHEDPIN();
        __builtin_amdgcn_s_setprio(1);
        #pragma unroll
        for(int m=0;m<4;m++)
            #pragma unroll
            for(int n=0;n<2;n++){
                acc[4+m][n] = MFMA16(af[m][0], bfv[n][0], acc[4+m][n]);
                acc[4+m][n] = MFMA16(af[m][1], bfv[n][1], acc[4+m][n]);
            }
        __builtin_amdgcn_s_setprio(0);
        __builtin_amdgcn_s_barrier();

        // ---- P4: stage B(k+2)h1; MFMA (mh1, nh1); counted gate
        if(stB){ SB1(k+2,1,0); SB1(k+2,1,1); }
        __builtin_amdgcn_s_barrier();
        __builtin_amdgcn_s_setprio(1);
        #pragma unroll
        for(int m=0;m<4;m++)
            #pragma unroll
            for(int n=2;n<4;n++){
                acc[4+m][n] = MFMA16(af[m][0], bfv[n][0], acc[4+m][n]);
                acc[4+m][n] = MFMA16(af[m][1], bfv[n][1], acc[4+m][n]);
            }
        __builtin_amdgcn_s_setprio(0);
        if(stB)      { WAITVM4(); }     // A(k+1)+B(k+1) landed; B(k+2)'s 4 in flight
        else if(stA) { WAITVM0(); }
        __builtin_amdgcn_s_barrier();
    }
#undef SA1
#undef SB1

    const float* be = bias + (size_t)e * N;
    #pragma unroll
    for(int mi=0;mi<8;mi++){
        int rbse = wm*128 + mi*16 + g*4;
        #pragma unroll
        for(int j=0;j<4;j++){
            int r = rbse + j;
            if(r >= valid) continue;
            size_t grow = (size_t)(row0 + r);
            #pragma unroll
            for(int n=0;n<4;n++){
                int col = n0 + wn*64 + n*16 + rl;
                float v = acc[mi][n][j] + be[col];
                v = 0.5f * v * (1.f + erff(v * 0.70710678118654752f));
                OutH[grow * (size_t)N + col] = f2bf(v);
            }
        }
    }
}

// ---------------- GEMM2: frozen R8/R12 128x128 kernel (atomic fused combine) ----------------
__global__ __launch_bounds__(256, 3) void k_gemm2(const unsigned short* __restrict__ A,
                                                  const unsigned short* __restrict__ Bw,
                                                  const float* __restrict__ bias,
                                                  const int* __restrict__ t1e,
                                                  const int* __restrict__ t1r,
                                                  const int* __restrict__ t1v,
                                                  const int* __restrict__ slot_token,
                                                  const float* __restrict__ slot_w,
                                                  float* __restrict__ outF)
{
    const int K = DFF, N = DMODEL;
    int xb = blockIdx.x;
    int tid = (xb & 7) * 9 + (xb >> 3);     // XCD-chunked bijective swizzle (72 = 8*9)
    int valid = t1v[tid];
    if(valid == 0) return;
    int e = t1e[tid], row0 = t1r[tid];
    int n0 = blockIdx.y * 128;
    const unsigned short* Be = Bw + (size_t)e * N * K;

    __shared__ unsigned short As[128*64];
    __shared__ unsigned short Bs[128*64];

    int t = threadIdx.x;
    int lane = t & 63;
    int wid = t >> 6;
    int wr = wid >> 1, wc = wid & 1;

    int srow = t >> 3;
    int csw  = (t & 7) ^ (srow & 7);
    const unsigned short* arow[4];
    const unsigned short* brow[4];
    #pragma unroll
    for(int i=0;i<4;i++){
        int r = i*32 + srow;
        arow[i] = A  + (size_t)(row0 + r) * (size_t)K + csw*8;
        brow[i] = Be + (size_t)(n0 + r)*K + csw*8;
    }
    unsigned short* alds = As + (size_t)t * 8;
    unsigned short* blds = Bs + (size_t)t * 8;

    f32x4 acc[4][4];
    #pragma unroll
    for(int m=0;m<4;m++)
        #pragma unroll
        for(int n=0;n<4;n++)
            acc[m][n] = (f32x4){0.f,0.f,0.f,0.f};

    int rl = lane & 15;
    int g  = lane >> 4;
    int rx = rl & 7;

    for(int k0=0;k0<K;k0+=64){
        __syncthreads();
        #pragma unroll
        for(int i=0;i<4;i++){
            gload16(arow[i] + k0, alds + i*2048);
            gload16(brow[i] + k0, blds + i*2048);
        }
        __syncthreads();

        #pragma unroll
        for(int kb=0;kb<2;kb++){
            int sw = ((kb*4 + g) ^ rx) * 8;
            bf16x8 af[4], bfv[4];
            #pragma unroll
            for(int m=0;m<4;m++) af[m]  = *(const bf16x8*)&As[(wr*64 + m*16 + rl)*64 + sw];
            #pragma unroll
            for(int n=0;n<4;n++) bfv[n] = *(const bf16x8*)&Bs[(wc*64 + n*16 + rl)*64 + sw];
            #pragma unroll
            for(int m=0;m<4;m++)
                #pragma unroll
                for(int n=0;n<4;n++)
                    acc[m][n] = MFMA16(af[m], bfv[n], acc[m][n]);
        }
    }

    const float* be = bias + (size_t)e * N;
    #pragma unroll
    for(int m=0;m<4;m++){
        int rb = wr*64 + m*16 + g*4;
        #pragma unroll
        for(int j=0;j<4;j++){
            int r = rb + j;
            if(r >= valid) continue;
            size_t grow = (size_t)(row0 + r);
            float wsc = slot_w[grow];
            float* orow = outF + (size_t)slot_token[grow] * DMODEL;
            #pragma unroll
            for(int n=0;n<4;n++){
                int col = n0 + wc*64 + n*16 + rl;
                float v = (acc[m][n][j] + be[col]) * wsc;
                atomicAdd(&orow[col], v);
            }
        }
    }
}

extern "C" void kernel_launch(void* const* d_in, const int* in_sizes, int n_in,
                              void* d_out, int out_size, void* d_ws, size_t ws_size,
                              hipStream_t stream)
{
    const float* x  = (const float*)d_in[0];
    const float* W1 = (const float*)d_in[1];
    const float* b1 = (const float*)d_in[2];
    const float* W2 = (const float*)d_in[3];
    const float* b2 = (const float*)d_in[4];
    const float* Wg = (const float*)d_in[5];
    const float* bg = (const float*)d_in[6];
    float* out = (float*)d_out;

    char* p = (char*)d_ws;
    auto alloc = [&](size_t bytes)->char*{
        char* r = p; p += (bytes + 255) & ~(size_t)255; return r;
    };
    unsigned short* W1t = (unsigned short*)alloc((size_t)NEXP*DFF*DMODEL*2);   // [E][DFF][DMODEL]
    unsigned short* W2t = (unsigned short*)alloc((size_t)NEXP*DMODEL*DFF*2);   // [E][DMODEL][DFF]
    unsigned short* Xb  = (unsigned short*)alloc((size_t)NTOK*DMODEL*2);
    unsigned short* H   = (unsigned short*)alloc((size_t)MAXSLOT*DFF*2);
    int*   slot_token = (int*)alloc(MAXSLOT*4);
    float* slot_w     = (float*)alloc(MAXSLOT*4);
    int*   token_e    = (int*)alloc(NSLOT*4);
    float* token_w    = (float*)alloc(NSLOT*4);
    int*   cnt        = (int*)alloc(64);
    int*   cursor     = (int*)alloc(64);
    int*   t2e = (int*)alloc(NT2*4);
    int*   t2r = (int*)alloc(NT2*4);
    int*   t2v = (int*)alloc(NT2*4);
    int*   t1e = (int*)alloc(NT1*4);
    int*   t1r = (int*)alloc(NT1*4);
    int*   t1v = (int*)alloc(NT1*4);
    (void)ws_size; (void)in_sizes; (void)n_in; (void)out_size;

    hipMemsetAsync(cnt, 0, 64, stream);
    // gate ∥ W1-transpose
    k_gate_w1t<<<3072, 256, 0, stream>>>(x, Wg, bg, W1, Xb, W1t, out,
                                         token_e, token_w, cnt);
    k_prefix<<<1, 256, 0, stream>>>(cnt, t2e, t2r, t2v, t1e, t1r, t1v, cursor, slot_token);
    k_scatter<<<NSLOT/256, 256, 0, stream>>>(token_e, token_w, cursor, slot_token, slot_w);
    // GEMM1 (256² 8-phase, X gather x W1t -> H, gelu) ∥ W2-transpose rider (y<4)
    k_gemm1<<<dim3(NT2, 20), 512, 0, stream>>>(
        Xb, W1t, b1, t2e, t2r, t2v, slot_token, H, W2, W2t);
    // GEMM2 (frozen 128²): H x W2t -> out (atomic fused combine)
    k_gemm2<<<dim3(NT1, DMODEL/128), 256, 0, stream>>>(
        H, W2t, b2, t1e, t1r, t1v, slot_token, slot_w, out);
}

// Round 18
// 428.994 us; speedup vs baseline: 1.0449x; 1.0449x over previous
//
#include <hip/hip_runtime.h>
#include <hip/hip_bf16.h>

#define NTOK   4096
#define DMODEL 1024
#define DFF    4096
#define NEXP   8
#define TOPK   2
#define BM 128
#define BN 128
#define BK 64
#define NSLOT   (NTOK*TOPK)            // 8192
#define MAXSLOT (NSLOT + NEXP*BM)      // 9216
#define MAXTILE (MAXSLOT/BM)           // 72 = 8 XCDs * 9
#define NWTILE  8192                   // 64x64 tiles per weight tensor (8 experts)

typedef __attribute__((ext_vector_type(8))) short bf16x8;
typedef __attribute__((ext_vector_type(8))) unsigned short u16x8;
typedef __attribute__((ext_vector_type(4))) float f32x4;

__device__ __forceinline__ unsigned short f2bf(float f){
    union { float f; unsigned int u; } v; v.f = f;
    unsigned int r = (v.u + 0x7fffu + ((v.u >> 16) & 1u)) >> 16;
    return (unsigned short)r;
}

__device__ __forceinline__ void gload16(const unsigned short* g, unsigned short* l){
    __builtin_amdgcn_global_load_lds(
        (const __attribute__((address_space(1))) void*)g,
        (__attribute__((address_space(3))) void*)l,
        16, 0, 0);
}

// ---- proven 64x64 fp32-LDS transpose-convert tile: dst[c0+c][r0+r] = bf16(src[r0+r][c0+c]) ----
__device__ __forceinline__ void transpose_tile64(const float* __restrict__ src,
                                                 unsigned short* __restrict__ dst,
                                                 int R, int C, int r0, int c0,
                                                 float (*tile)[65])
{
    int t = threadIdx.x;
    int tr  = t >> 4;          // 0..15
    int tc4 = (t & 15) * 4;    // 0..60
    #pragma unroll
    for(int i=0;i<4;i++){
        float4 v = *(const float4*)&src[(size_t)(r0 + tr + i*16)*C + c0 + tc4];
        tile[tc4+0][tr + i*16] = v.x;
        tile[tc4+1][tr + i*16] = v.y;
        tile[tc4+2][tr + i*16] = v.z;
        tile[tc4+3][tr + i*16] = v.w;
    }
    __syncthreads();
    int cr = t >> 3;           // 0..31
    int rb = (t & 7) * 8;      // 0..56
    #pragma unroll
    for(int i=0;i<2;i++){
        int c = cr + i*32;
        u16x8 o;
        #pragma unroll
        for(int q=0;q<8;q++) o[q] = f2bf(tile[c][rb + q]);
        *(u16x8*)&dst[(size_t)(c0 + c)*R + r0 + rb] = o;
    }
    __syncthreads();
}

// ---------------- fused: gating (+x convert + out zero) ∥ W1 transpose-convert ----------------
// grid 3072: x%3==0 -> gate block (1024), else -> W1-transpose worker (2048, 4 tiles each)
__global__ __launch_bounds__(256) void k_gate_w1t(const float* __restrict__ x,
                                                  const float* __restrict__ Wg,
                                                  const float* __restrict__ bg,
                                                  const float* __restrict__ W1,
                                                  unsigned short* __restrict__ Xb,
                                                  unsigned short* __restrict__ W1t,
                                                  float* __restrict__ out,
                                                  int* __restrict__ token_e,
                                                  float* __restrict__ token_w,
                                                  int* __restrict__ cnt)
{
    __shared__ float tile[64][65];
    int bx = blockIdx.x;
    if(bx % 3 != 0){
        int w = bx - bx/3 - 1;                 // 0..2047
        for(int t2 = w; t2 < NWTILE; t2 += 2048){
            int z  = t2 >> 10;                 // expert
            int rem = t2 & 1023;
            int rt = rem >> 6;                 // 0..15  (DMODEL/64 src-row tiles)
            int ct = rem & 63;                 // 0..63  (DFF/64 src-col tiles)
            transpose_tile64(W1 + (size_t)z*DMODEL*DFF, W1t + (size_t)z*DMODEL*DFF,
                             DMODEL, DFF, rt*64, ct*64, tile);
        }
        return;
    }
    int b = bx / 3;                            // gate block 0..1023
    int tid = threadIdx.x;
    const float4* xs = (const float4*)x + (size_t)b * 1024;
    ushort4* xd = (ushort4*)Xb + (size_t)b * 1024;
    float4* oz = (float4*)out + (size_t)b * 1024;
    float4 z4 = {0.f,0.f,0.f,0.f};
    #pragma unroll
    for(int rep=0;rep<4;rep++){
        float4 v = xs[rep*256 + tid];
        ushort4 o; o.x=f2bf(v.x); o.y=f2bf(v.y); o.z=f2bf(v.z); o.w=f2bf(v.w);
        xd[rep*256 + tid] = o;
        oz[rep*256 + tid] = z4;                // zero the fused-combine accumulator rows
    }

    int wid = tid >> 6, lane = tid & 63;
    int t = b * 4 + wid;
    const float* xr = x + (size_t)t * DMODEL;
    float pe[NEXP];
    #pragma unroll
    for(int e=0;e<NEXP;e++) pe[e] = 0.f;
    for(int i=0;i<DMODEL/64;i++){
        int d = i*64 + lane;
        float xv = xr[d];
        const float* wr = Wg + (size_t)d * NEXP;
        #pragma unroll
        for(int e=0;e<NEXP;e++) pe[e] += xv * wr[e];
    }
    #pragma unroll
    for(int off=32; off>0; off>>=1){
        #pragma unroll
        for(int e=0;e<NEXP;e++) pe[e] += __shfl_xor(pe[e], off);
    }
    if(lane == 0){
        float lg[NEXP], mx = -1e30f;
        #pragma unroll
        for(int e=0;e<NEXP;e++){ lg[e] = pe[e] + bg[e]; mx = fmaxf(mx, lg[e]); }
        float pr[NEXP];
        #pragma unroll
        for(int e=0;e<NEXP;e++) pr[e] = expf(lg[e] - mx);
        int e0 = 0; float p0 = pr[0];
        #pragma unroll
        for(int e=1;e<NEXP;e++) if(pr[e] > p0){ p0 = pr[e]; e0 = e; }
        int e1 = -1; float p1 = -1.f;
        #pragma unroll
        for(int e=0;e<NEXP;e++) if(e != e0 && pr[e] > p1){ p1 = pr[e]; e1 = e; }
        float dn = p0 + p1;
        token_e[2*t]   = e0; token_w[2*t]   = p0/dn;
        token_e[2*t+1] = e1; token_w[2*t+1] = p1/dn;
        atomicAdd(&cnt[e0], 1); atomicAdd(&cnt[e1], 1);
    }
}

// ---------------- prefix: tile table + global cursor init + pad prefill (1 block) ----------------
__global__ __launch_bounds__(256) void k_prefix(const int* __restrict__ cnt,
                                                int* __restrict__ tile_e,
                                                int* __restrict__ tile_row0,
                                                int* __restrict__ tile_valid,
                                                int* __restrict__ cursor,
                                                int* __restrict__ slot_token)
{
    int tid = threadIdx.x;
    if(tid == 0){
        int off = 0, nt = 0;
        for(int e=0;e<NEXP;e++){
            cursor[e] = off;
            int c = cnt[e];
            for(int r=0;r<c;r+=BM){
                tile_e[nt] = e; tile_row0[nt] = off + r;
                tile_valid[nt] = (c - r < BM) ? (c - r) : BM;
                nt++;
            }
            off += ((c + BM - 1)/BM)*BM;
        }
        for(int i=nt;i<MAXTILE;i++){ tile_e[i]=0; tile_row0[i]=0; tile_valid[i]=0; }
    }
    for(int s=tid; s<MAXSLOT; s+=256) slot_token[s] = 0;  // safe gather addr for pad rows
}

// ---------------- scatter: 32 blocks, global cursor atomics ----------------
__global__ __launch_bounds__(256) void k_scatter(const int* __restrict__ token_e,
                                                 const float* __restrict__ token_w,
                                                 int* __restrict__ cursor,
                                                 int* __restrict__ slot_token,
                                                 float* __restrict__ slot_w)
{
    int i = blockIdx.x*256 + threadIdx.x;
    int e = token_e[i];
    int s = atomicAdd(&cursor[e], 1);
    slot_token[s] = i >> 1;
    slot_w[s] = token_w[i];
}

// ---------------- grouped GEMM tile kernel (R8/R12 FROZEN loop) + optional fused W2 transpose ----------------
// FUSET: grid y=40; y in {4,9,...,39} -> W2-transpose worker (576 total, ~14 tiles each);
// other 32 y-rows are the GEMM N-blocks (n = y - (y+1)/5).
template<bool GATHER, bool GELU, bool FUSET>
__global__ __launch_bounds__(256, 3) void k_gemm(const unsigned short* __restrict__ A,
                                                 const unsigned short* __restrict__ Bw,
                                                 const float* __restrict__ bias,
                                                 const int* __restrict__ tile_e,
                                                 const int* __restrict__ tile_row0,
                                                 const int* __restrict__ tile_valid,
                                                 const int* __restrict__ slot_token,
                                                 const float* __restrict__ slot_w,
                                                 unsigned short* __restrict__ OutH,
                                                 float* __restrict__ outF,
                                                 const float* __restrict__ Wsrc,
                                                 unsigned short* __restrict__ Wdst,
                                                 int K, int N)
{
    __shared__ __align__(16) unsigned short SM[BM*BK + BN*BK];   // 32 KB
    unsigned short* As = SM;
    unsigned short* Bs = SM + BM*BK;

    int y = blockIdx.y;
    if(FUSET && ((y+1) % 5) == 0){
        float (*tile)[65] = (float(*)[65])SM;                    // 16.6 KB alias
        int w = blockIdx.x * 8 + (y/5);                          // 0..575
        for(int t2 = w; t2 < NWTILE; t2 += 576){
            int z  = t2 >> 10;
            int rem = t2 & 1023;
            int rt = rem >> 4;                                   // 0..63 (DFF/64 src-row tiles)
            int ct = rem & 15;                                   // 0..15 (DMODEL/64 src-col tiles)
            transpose_tile64(Wsrc + (size_t)z*DFF*DMODEL, Wdst + (size_t)z*DFF*DMODEL,
                             DFF, DMODEL, rt*64, ct*64, tile);
        }
        return;
    }

    int xb = blockIdx.x;
    int tid = (xb & 7) * (MAXTILE/8) + (xb >> 3);   // XCD-chunked bijective swizzle (72 = 8*9)
    int valid = tile_valid[tid];
    if(valid == 0) return;
    int e = tile_e[tid];
    int row0 = tile_row0[tid];
    int n0 = (FUSET ? (y - (y+1)/5) : y) * BN;
    const unsigned short* Be = Bw + (size_t)e * N * K;

    int t = threadIdx.x;
    int lane = t & 63;
    int wid = t >> 6;
    int wr = wid >> 1, wc = wid & 1;

    // staging: thread t, issue i stages LDS chunk p = i*256+t (16B chunks)
    // row r = i*32 + (t>>3), phys chunk c = t&7; content = global chunk c ^ (r&7)
    int srow = t >> 3;                      // 0..31
    int csw  = (t & 7) ^ (srow & 7);        // swizzled source chunk
    const unsigned short* arow[4];
    const unsigned short* brow[4];
    #pragma unroll
    for(int i=0;i<4;i++){
        int r = i*32 + srow;
        size_t aoff;
        if(GATHER) aoff = (size_t)slot_token[row0 + r] * (size_t)K;
        else       aoff = (size_t)(row0 + r) * (size_t)K;
        arow[i] = A  + aoff + csw*8;
        brow[i] = Be + (size_t)(n0 + r)*K + csw*8;
    }
    unsigned short* alds = As + (size_t)t * 8;
    unsigned short* blds = Bs + (size_t)t * 8;

    f32x4 acc[4][4];
    #pragma unroll
    for(int m=0;m<4;m++)
        #pragma unroll
        for(int n=0;n<4;n++)
            acc[m][n] = (f32x4){0.f,0.f,0.f,0.f};

    int rl = lane & 15;
    int g  = lane >> 4;
    int rx = rl & 7;

    for(int k0=0;k0<K;k0+=BK){
        __syncthreads();   // previous compute done before LDS overwrite
        #pragma unroll
        for(int i=0;i<4;i++){
            gload16(arow[i] + k0, alds + i*2048);
            gload16(brow[i] + k0, blds + i*2048);
        }
        __syncthreads();   // compiler drains vmcnt(0) before barrier -> tile ready

        #pragma unroll
        for(int kb=0;kb<2;kb++){
            int sw = ((kb*4 + g) ^ rx) * 8;   // proven conflict-free swizzled chunk offset
            bf16x8 af[4], bfv[4];
            #pragma unroll
            for(int m=0;m<4;m++) af[m]  = *(const bf16x8*)&As[(wr*64 + m*16 + rl)*BK + sw];
            #pragma unroll
            for(int n=0;n<4;n++) bfv[n] = *(const bf16x8*)&Bs[(wc*64 + n*16 + rl)*BK + sw];
            #pragma unroll
            for(int m=0;m<4;m++)
                #pragma unroll
                for(int n=0;n<4;n++)
                    acc[m][n] = __builtin_amdgcn_mfma_f32_16x16x32_bf16(af[m], bfv[n], acc[m][n], 0, 0, 0);
        }
    }

    const float* be = bias + (size_t)e * N;
    #pragma unroll
    for(int m=0;m<4;m++){
        int rb = wr*64 + m*16 + g*4;
        #pragma unroll
        for(int j=0;j<4;j++){
            int r = rb + j;
            if(r >= valid) continue;
            size_t grow = (size_t)(row0 + r);
            if(GELU){
                #pragma unroll
                for(int n=0;n<4;n++){
                    int col = n0 + wc*64 + n*16 + rl;
                    float v = acc[m][n][j] + be[col];
                    v = 0.5f * v * (1.f + erff(v * 0.70710678118654752f));
                    OutH[grow * (size_t)N + col] = f2bf(v);
                }
            } else {
                float wsc = slot_w[grow];
                float* orow = outF + (size_t)slot_token[grow] * DMODEL;
                #pragma unroll
                for(int n=0;n<4;n++){
                    int col = n0 + wc*64 + n*16 + rl;
                    float v = (acc[m][n][j] + be[col]) * wsc;
                    atomicAdd(&orow[col], v);
                }
            }
        }
    }
}

extern "C" void kernel_launch(void* const* d_in, const int* in_sizes, int n_in,
                              void* d_out, int out_size, void* d_ws, size_t ws_size,
                              hipStream_t stream)
{
    const float* x  = (const float*)d_in[0];
    const float* W1 = (const float*)d_in[1];
    const float* b1 = (const float*)d_in[2];
    const float* W2 = (const float*)d_in[3];
    const float* b2 = (const float*)d_in[4];
    const float* Wg = (const float*)d_in[5];
    const float* bg = (const float*)d_in[6];
    float* out = (float*)d_out;

    char* p = (char*)d_ws;
    auto alloc = [&](size_t bytes)->char*{
        char* r = p; p += (bytes + 255) & ~(size_t)255; return r;
    };
    unsigned short* W1t = (unsigned short*)alloc((size_t)NEXP*DFF*DMODEL*2);   // [E][DFF][DMODEL]
    unsigned short* W2t = (unsigned short*)alloc((size_t)NEXP*DMODEL*DFF*2);   // [E][DMODEL][DFF]
    unsigned short* Xb  = (unsigned short*)alloc((size_t)NTOK*DMODEL*2);
    unsigned short* H   = (unsigned short*)alloc((size_t)MAXSLOT*DFF*2);
    int*   slot_token = (int*)alloc(MAXSLOT*4);
    float* slot_w     = (float*)alloc(MAXSLOT*4);
    int*   token_e    = (int*)alloc(NSLOT*4);
    float* token_w    = (float*)alloc(NSLOT*4);
    int*   cnt        = (int*)alloc(64);
    int*   cursor     = (int*)alloc(64);
    int*   tile_e     = (int*)alloc(MAXTILE*4);
    int*   tile_row0  = (int*)alloc(MAXTILE*4);
    int*   tile_valid = (int*)alloc(MAXTILE*4);
    (void)ws_size; (void)in_sizes; (void)n_in; (void)out_size;

    hipMemsetAsync(cnt, 0, 64, stream);
    // gate ∥ W1-transpose (gate's 42 MB hides under W1T's 201 MB)
    k_gate_w1t<<<3072, 256, 0, stream>>>(x, Wg, bg, W1, Xb, W1t, out,
                                         token_e, token_w, cnt);
    k_prefix<<<1, 256, 0, stream>>>(cnt, tile_e, tile_row0, tile_valid, cursor, slot_token);
    k_scatter<<<NSLOT/256, 256, 0, stream>>>(token_e, token_w, cursor, slot_token, slot_w);
    // GEMM1 (X gather x W1t -> H, gelu) ∥ W2-transpose (hidden in GEMM1's BW headroom).
    // grid 72 x 40: 32 y-rows GEMM N-blocks + 8 y-rows (576 blocks) transpose workers.
    k_gemm<true, true, true ><<<dim3(MAXTILE, 40), 256, 0, stream>>>(
        Xb, W1t, b1, tile_e, tile_row0, tile_valid, slot_token, slot_w, H, nullptr,
        W2, W2t, DMODEL, DFF);
    // GEMM2: H x W2t -> out (atomic fused combine).  grid 72 x 8, K=4096
    k_gemm<false,false,false><<<dim3(MAXTILE, DMODEL/BN), 256, 0, stream>>>(
        H,  W2t, b2, tile_e, tile_row0, tile_valid, slot_token, slot_w, nullptr, out,
        nullptr, nullptr, DFF, DMODEL);
}